// Round 1
// baseline (231.029 us; speedup 1.0000x reference)
//
#include <hip/hip_runtime.h>
#include <hip/hip_bf16.h>

// Switch MoE (top-1), B=2 S=1024 H=768 F=3072 E=8 on MI355X.
// Outputs concat in d_out: next_states[2048*768] f32, router_logits[2048*8] f32,
// expert_index[2048] written as float values.

#define T_TOKENS 2048
#define H_DIM 768
#define F_DIM 3072
#define E_NUM 8

typedef __attribute__((ext_vector_type(8))) short bf16x8;
typedef __attribute__((ext_vector_type(4))) float f32x4;

__device__ inline unsigned short f2bf(float f) {
  __hip_bfloat16 b = __float2bfloat16(f);
  return *reinterpret_cast<unsigned short*>(&b);
}

// ---------------- Router: one wave per token ----------------
__global__ void router_kernel(const float* __restrict__ X, const float* __restrict__ Wr,
                              float* __restrict__ logits, float* __restrict__ idx_out,
                              int* __restrict__ expert, float* __restrict__ prob,
                              int* __restrict__ counts) {
  int wave = threadIdx.x >> 6, lane = threadIdx.x & 63;
  int t = blockIdx.x * 4 + wave;
  if (t >= T_TOKENS) return;
  const float* x = X + (size_t)t * H_DIM;
  float acc[E_NUM];
#pragma unroll
  for (int e = 0; e < E_NUM; ++e) acc[e] = 0.f;
  int h0 = lane * 12;  // 64 lanes * 12 = 768
#pragma unroll
  for (int j = 0; j < 12; ++j) {
    float xv = x[h0 + j];
    const float4* wr = reinterpret_cast<const float4*>(Wr + (size_t)(h0 + j) * E_NUM);
    float4 w0 = wr[0], w1 = wr[1];
    acc[0] += xv * w0.x; acc[1] += xv * w0.y; acc[2] += xv * w0.z; acc[3] += xv * w0.w;
    acc[4] += xv * w1.x; acc[5] += xv * w1.y; acc[6] += xv * w1.z; acc[7] += xv * w1.w;
  }
#pragma unroll
  for (int e = 0; e < E_NUM; ++e) {
#pragma unroll
    for (int s = 32; s > 0; s >>= 1) acc[e] += __shfl_down(acc[e], s);
  }
  if (lane == 0) {
    float m = acc[0]; int am = 0;
#pragma unroll
    for (int e = 1; e < E_NUM; ++e) {
      if (acc[e] > m) { m = acc[e]; am = e; }  // strict > keeps first occurrence (jnp.argmax)
    }
    float sum = 0.f;
#pragma unroll
    for (int e = 0; e < E_NUM; ++e) sum += __expf(acc[e] - m);
    float p = 1.f / sum;  // softmax prob of the argmax
#pragma unroll
    for (int e = 0; e < E_NUM; ++e) logits[(size_t)t * E_NUM + e] = acc[e];
    idx_out[t] = (float)am;
    expert[t] = am;
    prob[t] = p;
    atomicAdd(&counts[am], 1);
  }
}

// ---------------- Exclusive scan of 8 counts ----------------
__global__ void scan_kernel(const int* __restrict__ counts, int* __restrict__ offs) {
  if (threadIdx.x == 0) {
    int s = 0;
    for (int e = 0; e < E_NUM; ++e) { offs[e] = s; s += counts[e]; }
    offs[E_NUM] = s;
  }
}

// ---------------- Scatter token ids into per-expert segments ----------------
__global__ void scatter_kernel(const int* __restrict__ expert, const int* __restrict__ offs,
                               int* __restrict__ cursor, int* __restrict__ perm) {
  int t = blockIdx.x * blockDim.x + threadIdx.x;
  if (t < T_TOKENS) {
    int e = expert[t];
    int pos = atomicAdd(&cursor[e], 1);
    perm[offs[e] + pos] = t;
  }
}

// ---------------- Gather X rows -> contiguous bf16, one wave per row ----------------
__global__ void gather_kernel(const float* __restrict__ X, const int* __restrict__ perm,
                              __hip_bfloat16* __restrict__ xg) {
  int wave = threadIdx.x >> 6, lane = threadIdx.x & 63;
  int g = blockIdx.x * 4 + wave;
  if (g >= T_TOKENS) return;
  int token = perm[g];
  const float4* src = reinterpret_cast<const float4*>(X + (size_t)token * H_DIM + lane * 12);
  __hip_bfloat16* dst = xg + (size_t)g * H_DIM + lane * 12;
#pragma unroll
  for (int i = 0; i < 3; ++i) {
    float4 v = src[i];
    ushort4 u;
    u.x = f2bf(v.x); u.y = f2bf(v.y); u.z = f2bf(v.z); u.w = f2bf(v.w);
    *reinterpret_cast<ushort4*>(dst + i * 4) = u;
  }
}

// ---------------- Grouped GEMM: C[m,n] = sum_k A[m,k] * W[e][k,n] ----------------
// A: gathered bf16 rows (row-major, stride K). W: f32 [E][K][N] row-major,
// converted+transposed into LDS tiles on the fly.
// RELU=1: write bf16 h to Cbf (gathered order). RELU=0: scale by prob, scatter f32 by perm.
template <int RELU>
__global__ __launch_bounds__(256) void moe_gemm(
    const __hip_bfloat16* __restrict__ A, const float* __restrict__ Wt,
    __hip_bfloat16* __restrict__ Cbf, float* __restrict__ Cf,
    const int* __restrict__ offs, const int* __restrict__ perm,
    const float* __restrict__ prob, int K, int N) {
  constexpr int BM = 128, BN = 128, BK = 32, LDP = BK + 8;  // +8 bf16 pad (16B-aligned rows)
  __shared__ __hip_bfloat16 As[BM][LDP];
  __shared__ __hip_bfloat16 Bs[BN][LDP];  // transposed: Bs[n][k]

  int e = blockIdx.z;
  int base = offs[e], cnt = offs[e + 1] - base;
  int m0 = blockIdx.y * BM;
  if (m0 >= cnt) return;
  int rows = min(BM, cnt - m0);
  int n0 = blockIdx.x * BN;
  const __hip_bfloat16* Ab = A + (size_t)(base + m0) * K;
  const float* W = Wt + (size_t)e * K * N;

  int tid = threadIdx.x;
  int lane = tid & 63, wv = tid >> 6;
  int wr = wv >> 1, wc = wv & 1;         // 2x2 waves, each 64x64
  int lr = lane & 15, ks = (lane >> 4) * 8;

  f32x4 acc[4][4];
#pragma unroll
  for (int i = 0; i < 4; ++i)
#pragma unroll
    for (int j = 0; j < 4; ++j) acc[i][j] = (f32x4){0.f, 0.f, 0.f, 0.f};

  // A staging: 128 rows x 32 cols bf16; thread -> (row, 16-col half)
  int ar = tid >> 1, ac = (tid & 1) * 16;
  // B staging: 32 k-rows x 128 n-cols f32; thread -> (2 k-rows, 8 n-cols)
  int bk = (tid >> 4) * 2, bn = (tid & 15) * 8;

  for (int k0 = 0; k0 < K; k0 += BK) {
    // ---- global loads into registers ----
    int4 a0 = {0, 0, 0, 0}, a1 = {0, 0, 0, 0};
    if (ar < rows) {
      const int4* src = reinterpret_cast<const int4*>(Ab + (size_t)ar * K + k0 + ac);
      a0 = src[0];
      a1 = src[1];
    }
    const float4* b0p = reinterpret_cast<const float4*>(W + (size_t)(k0 + bk) * N + n0 + bn);
    const float4* b1p = reinterpret_cast<const float4*>(W + (size_t)(k0 + bk + 1) * N + n0 + bn);
    float4 b00 = b0p[0], b01 = b0p[1];
    float4 b10 = b1p[0], b11 = b1p[1];

    __syncthreads();  // previous iteration's MFMA reads done

    // ---- LDS writes ----
    *reinterpret_cast<int4*>(&As[ar][ac]) = a0;
    *reinterpret_cast<int4*>(&As[ar][ac + 8]) = a1;
    float v0[8] = {b00.x, b00.y, b00.z, b00.w, b01.x, b01.y, b01.z, b01.w};
    float v1[8] = {b10.x, b10.y, b10.z, b10.w, b11.x, b11.y, b11.z, b11.w};
#pragma unroll
    for (int j = 0; j < 8; ++j) {
      unsigned int pk = (unsigned int)f2bf(v0[j]) | ((unsigned int)f2bf(v1[j]) << 16);
      *reinterpret_cast<unsigned int*>(&Bs[bn + j][bk]) = pk;
    }
    __syncthreads();

    // ---- MFMA ----
    bf16x8 af[4], bfr[4];
#pragma unroll
    for (int mi = 0; mi < 4; ++mi)
      af[mi] = *reinterpret_cast<const bf16x8*>(&As[wr * 64 + mi * 16 + lr][ks]);
#pragma unroll
    for (int ni = 0; ni < 4; ++ni)
      bfr[ni] = *reinterpret_cast<const bf16x8*>(&Bs[wc * 64 + ni * 16 + lr][ks]);
#pragma unroll
    for (int mi = 0; mi < 4; ++mi)
#pragma unroll
      for (int ni = 0; ni < 4; ++ni)
        acc[mi][ni] = __builtin_amdgcn_mfma_f32_16x16x32_bf16(af[mi], bfr[ni], acc[mi][ni], 0, 0, 0);
  }

  // ---- epilogue ----
  int lg = lane >> 4;
#pragma unroll
  for (int mi = 0; mi < 4; ++mi) {
#pragma unroll
    for (int r = 0; r < 4; ++r) {
      int lrow = wr * 64 + mi * 16 + lg * 4 + r;
      if (lrow < rows) {
        if (RELU) {
          __hip_bfloat16* dst = Cbf + (size_t)(base + m0 + lrow) * N + n0 + wc * 64 + lr;
#pragma unroll
          for (int ni = 0; ni < 4; ++ni) {
            float v = acc[mi][ni][r];
            dst[ni * 16] = __float2bfloat16(v > 0.f ? v : 0.f);
          }
        } else {
          int token = perm[base + m0 + lrow];
          float p = prob[token];
          float* dst = Cf + (size_t)token * N + n0 + wc * 64 + lr;
#pragma unroll
          for (int ni = 0; ni < 4; ++ni) dst[ni * 16] = acc[mi][ni][r] * p;
        }
      }
    }
  }
}

extern "C" void kernel_launch(void* const* d_in, const int* in_sizes, int n_in,
                              void* d_out, int out_size, void* d_ws, size_t ws_size,
                              hipStream_t stream) {
  const float* X = (const float*)d_in[0];
  const float* Wr = (const float*)d_in[1];
  const float* W1 = (const float*)d_in[2];
  const float* W2 = (const float*)d_in[3];

  float* out_states = (float*)d_out;
  float* out_logits = out_states + (size_t)T_TOKENS * H_DIM;
  float* out_index = out_logits + (size_t)T_TOKENS * E_NUM;

  char* ws = (char*)d_ws;
  int* counts = (int*)(ws + 0);       // 8 ints
  int* cursor = (int*)(ws + 32);      // 8 ints
  int* offs = (int*)(ws + 64);        // 9 ints
  int* expert = (int*)(ws + 128);     // 2048 ints
  float* prob = (float*)(ws + 8320);  // 2048 f32
  int* perm = (int*)(ws + 16512);     // 2048 ints
  __hip_bfloat16* xg = (__hip_bfloat16*)(ws + 24704);      // 2048*768 bf16
  __hip_bfloat16* hbuf = (__hip_bfloat16*)(ws + 3170432);  // 2048*3072 bf16
  // total ws use ~15.76 MB

  hipMemsetAsync(d_ws, 0, 64, stream);  // zero counts + cursor

  router_kernel<<<T_TOKENS / 4, 256, 0, stream>>>(X, Wr, out_logits, out_index, expert, prob, counts);
  scan_kernel<<<1, 64, 0, stream>>>(counts, offs);
  scatter_kernel<<<T_TOKENS / 256, 256, 0, stream>>>(expert, offs, cursor, perm);
  gather_kernel<<<T_TOKENS / 4, 256, 0, stream>>>(X, perm, xg);

  // h = relu(xg @ W1[e]) : K=768, N=3072
  moe_gemm<1><<<dim3(F_DIM / 128, T_TOKENS / 128, E_NUM), 256, 0, stream>>>(
      xg, W1, hbuf, nullptr, offs, nullptr, nullptr, H_DIM, F_DIM);
  // y = (h @ W2[e]) * prob, scattered : K=3072, N=768
  moe_gemm<0><<<dim3(H_DIM / 128, T_TOKENS / 128, E_NUM), 256, 0, stream>>>(
      hbuf, W2, nullptr, out_states, offs, perm, prob, F_DIM, H_DIM);
}

// Round 2
// 170.155 us; speedup vs baseline: 1.3578x; 1.3578x over previous
//
#include <hip/hip_runtime.h>
#include <hip/hip_bf16.h>

// Switch MoE (top-1), B=2 S=1024 H=768 F=3072 E=8 on MI355X.
// Outputs concat in d_out: next_states[2048*768] f32, router_logits[2048*8] f32,
// expert_index[2048] written as float values.

#define T_TOKENS 2048
#define H_DIM 768
#define F_DIM 3072
#define E_NUM 8

typedef __attribute__((ext_vector_type(8))) short bf16x8;
typedef __attribute__((ext_vector_type(4))) float f32x4;

__device__ inline unsigned short f2bf(float f) {
  __hip_bfloat16 b = __float2bfloat16(f);
  return *reinterpret_cast<unsigned short*>(&b);
}
__device__ inline unsigned int pack2(float lo, float hi) {
  return (unsigned int)f2bf(lo) | ((unsigned int)f2bf(hi) << 16);
}

// ---------------- Router: one wave per token ----------------
__global__ void router_kernel(const float* __restrict__ X, const float* __restrict__ Wr,
                              float* __restrict__ logits, float* __restrict__ idx_out,
                              int* __restrict__ expert, float* __restrict__ prob,
                              int* __restrict__ counts) {
  int wave = threadIdx.x >> 6, lane = threadIdx.x & 63;
  int t = blockIdx.x * 4 + wave;
  if (t >= T_TOKENS) return;
  const float* x = X + (size_t)t * H_DIM;
  float acc[E_NUM];
#pragma unroll
  for (int e = 0; e < E_NUM; ++e) acc[e] = 0.f;
  int h0 = lane * 12;  // 64 lanes * 12 = 768
#pragma unroll
  for (int j = 0; j < 12; ++j) {
    float xv = x[h0 + j];
    const float4* wr = reinterpret_cast<const float4*>(Wr + (size_t)(h0 + j) * E_NUM);
    float4 w0 = wr[0], w1 = wr[1];
    acc[0] += xv * w0.x; acc[1] += xv * w0.y; acc[2] += xv * w0.z; acc[3] += xv * w0.w;
    acc[4] += xv * w1.x; acc[5] += xv * w1.y; acc[6] += xv * w1.z; acc[7] += xv * w1.w;
  }
#pragma unroll
  for (int e = 0; e < E_NUM; ++e) {
#pragma unroll
    for (int s = 32; s > 0; s >>= 1) acc[e] += __shfl_down(acc[e], s);
  }
  if (lane == 0) {
    float m = acc[0]; int am = 0;
#pragma unroll
    for (int e = 1; e < E_NUM; ++e) {
      if (acc[e] > m) { m = acc[e]; am = e; }  // strict > keeps first occurrence (jnp.argmax)
    }
    float sum = 0.f;
#pragma unroll
    for (int e = 0; e < E_NUM; ++e) sum += __expf(acc[e] - m);
    float p = 1.f / sum;  // softmax prob of the argmax
#pragma unroll
    for (int e = 0; e < E_NUM; ++e) logits[(size_t)t * E_NUM + e] = acc[e];
    idx_out[t] = (float)am;
    expert[t] = am;
    prob[t] = p;
    atomicAdd(&counts[am], 1);
  }
}

// ---------------- Exclusive scan of 8 counts ----------------
__global__ void scan_kernel(const int* __restrict__ counts, int* __restrict__ offs) {
  if (threadIdx.x == 0) {
    int s = 0;
    for (int e = 0; e < E_NUM; ++e) { offs[e] = s; s += counts[e]; }
    offs[E_NUM] = s;
  }
}

// ---------------- Scatter token ids into per-expert segments ----------------
__global__ void scatter_kernel(const int* __restrict__ expert, const int* __restrict__ offs,
                               int* __restrict__ cursor, int* __restrict__ perm) {
  int t = blockIdx.x * blockDim.x + threadIdx.x;
  if (t < T_TOKENS) {
    int e = expert[t];
    int pos = atomicAdd(&cursor[e], 1);
    perm[offs[e] + pos] = t;
  }
}

// ---------------- Gather X rows -> contiguous bf16, one wave per row ----------------
__global__ void gather_kernel(const float* __restrict__ X, const int* __restrict__ perm,
                              __hip_bfloat16* __restrict__ xg) {
  int wave = threadIdx.x >> 6, lane = threadIdx.x & 63;
  int g = blockIdx.x * 4 + wave;
  if (g >= T_TOKENS) return;
  int token = perm[g];
  const float4* src = reinterpret_cast<const float4*>(X + (size_t)token * H_DIM + lane * 12);
  __hip_bfloat16* dst = xg + (size_t)g * H_DIM + lane * 12;
#pragma unroll
  for (int i = 0; i < 3; ++i) {
    float4 v = src[i];
    ushort4 u;
    u.x = f2bf(v.x); u.y = f2bf(v.y); u.z = f2bf(v.z); u.w = f2bf(v.w);
    *reinterpret_cast<ushort4*>(dst + i * 4) = u;
  }
}

// ---------------- Grouped GEMM: C[m,n] = sum_k A[m,k] * W[e][k,n] ----------------
// BM=64, BK=64, BN template (128 for GEMM1, 64 for GEMM2). 4 waves as 2x2,
// wavetile 32 x BN/2. Double-buffered LDS, one barrier per K-step, next-tile
// global loads issued before the MFMA phase (latency hidden under compute).
// LDP=72 (144B rows): fragment ds_read_b128 rows hit distinct 16B slots (2-way, free).
// B is f32 [K][N]; transposed to bf16 Bs[n][k] via in-register k-packing (b128/b64 writes).
template <int RELU, int BN>
__global__ __launch_bounds__(256) void moe_gemm(
    const __hip_bfloat16* __restrict__ A, const float* __restrict__ Wt,
    __hip_bfloat16* __restrict__ Cbf, float* __restrict__ Cf,
    const int* __restrict__ offs, const int* __restrict__ perm,
    const float* __restrict__ prob, int K, int N) {
  constexpr int BM = 64, BK = 64, LDP = 72;
  constexpr int NI = BN / 32;        // B fragments per wave per ksub: 4 or 2
  constexpr int NCH = BN / 4;        // n-chunks of 4 floats: 32 or 16
  constexpr int RPT = NCH / 4;       // k-rows per staging thread: 8 or 4

  __shared__ __hip_bfloat16 As[2][BM][LDP];
  __shared__ __hip_bfloat16 Bs[2][BN][LDP];

  const int e = blockIdx.z;
  const int base = offs[e], cnt = offs[e + 1] - base;
  const int m0 = blockIdx.y * BM;
  if (m0 >= cnt) return;
  const int rows = min(BM, cnt - m0);
  const int n0 = blockIdx.x * BN;
  const __hip_bfloat16* __restrict__ Ab = A + (size_t)(base + m0) * K;
  const float* __restrict__ W = Wt + (size_t)e * K * N;

  const int tid = threadIdx.x;
  const int lane = tid & 63, wv = tid >> 6;
  const int wr = wv >> 1, wc = wv & 1;
  const int lr = lane & 15, lg = lane >> 4;

  // A staging: thread -> (row, 32B col chunk); rows beyond cnt clamp to a valid row.
  const int arow = tid >> 2, acol = (tid & 3) * 16;
  const __hip_bfloat16* Aptr = Ab + (size_t)min(arow, rows - 1) * K + acol;

  // B staging: thread -> (4 n-cols, RPT k-rows).
  const int bn4 = (tid & (NCH - 1)) * 4;
  const int bk = (tid / NCH) * RPT;
  const float* Bptr = W + (size_t)bk * N + n0 + bn4;

  f32x4 acc[2][NI];
#pragma unroll
  for (int i = 0; i < 2; ++i)
#pragma unroll
    for (int j = 0; j < NI; ++j) acc[i][j] = (f32x4){0.f, 0.f, 0.f, 0.f};

  int4 aR0, aR1;
  f32x4 f4[RPT];

#define LOAD_TILE(K0) do {                                                        \
    const int4* _s = reinterpret_cast<const int4*>(Aptr + (K0));                  \
    aR0 = _s[0]; aR1 = _s[1];                                                     \
    _Pragma("unroll")                                                             \
    for (int p = 0; p < RPT; ++p)                                                 \
      f4[p] = *reinterpret_cast<const f32x4*>(Bptr + (size_t)((K0) + p) * N);     \
  } while (0)

#define WRITE_TILE(BUF) do {                                                      \
    *reinterpret_cast<int4*>(&As[BUF][arow][acol]) = aR0;                         \
    *reinterpret_cast<int4*>(&As[BUF][arow][acol + 8]) = aR1;                     \
    _Pragma("unroll")                                                             \
    for (int cc = 0; cc < 4; ++cc) {                                              \
      if constexpr (BN == 128) {                                                  \
        int4 u;                                                                   \
        u.x = (int)pack2(f4[0][cc], f4[1][cc]);                                   \
        u.y = (int)pack2(f4[2][cc], f4[3][cc]);                                   \
        u.z = (int)pack2(f4[4][cc], f4[5][cc]);                                   \
        u.w = (int)pack2(f4[6][cc], f4[7][cc]);                                   \
        *reinterpret_cast<int4*>(&Bs[BUF][bn4 + cc][bk]) = u;                     \
      } else {                                                                    \
        int2 u;                                                                   \
        u.x = (int)pack2(f4[0][cc], f4[1][cc]);                                   \
        u.y = (int)pack2(f4[2][cc], f4[3][cc]);                                   \
        *reinterpret_cast<int2*>(&Bs[BUF][bn4 + cc][bk]) = u;                     \
      }                                                                           \
    }                                                                             \
  } while (0)

  // Prologue: stage tile 0.
  LOAD_TILE(0);
  WRITE_TILE(0);
  __syncthreads();

  const int nt = K / BK;
  int cb = 0;
  for (int t = 0; t < nt; ++t) {
    const bool pf = (t + 1) < nt;
    if (pf) LOAD_TILE((t + 1) * BK);  // issue early; consumed after MFMA phase

#pragma unroll
    for (int ks = 0; ks < 2; ++ks) {
      bf16x8 af[2], bv[NI];
#pragma unroll
      for (int mi = 0; mi < 2; ++mi)
        af[mi] = *reinterpret_cast<const bf16x8*>(&As[cb][wr * 32 + mi * 16 + lr][ks * 32 + lg * 8]);
#pragma unroll
      for (int ni = 0; ni < NI; ++ni)
        bv[ni] = *reinterpret_cast<const bf16x8*>(&Bs[cb][wc * (BN / 2) + ni * 16 + lr][ks * 32 + lg * 8]);
#pragma unroll
      for (int mi = 0; mi < 2; ++mi)
#pragma unroll
        for (int ni = 0; ni < NI; ++ni)
          acc[mi][ni] = __builtin_amdgcn_mfma_f32_16x16x32_bf16(af[mi], bv[ni], acc[mi][ni], 0, 0, 0);
    }

    if (pf) WRITE_TILE(cb ^ 1);  // buffer cb^1 free since barrier at end of t-1
    __syncthreads();
    cb ^= 1;
  }
#undef LOAD_TILE
#undef WRITE_TILE

  // ---- epilogue ----
#pragma unroll
  for (int mi = 0; mi < 2; ++mi) {
#pragma unroll
    for (int r = 0; r < 4; ++r) {
      int row = wr * 32 + mi * 16 + lg * 4 + r;
      if (row < rows) {
        if (RELU) {
          __hip_bfloat16* dst = Cbf + (size_t)(base + m0 + row) * N + n0 + wc * (BN / 2) + lr;
#pragma unroll
          for (int ni = 0; ni < NI; ++ni) {
            float v = acc[mi][ni][r];
            dst[ni * 16] = __float2bfloat16(v > 0.f ? v : 0.f);
          }
        } else {
          int token = perm[base + m0 + row];
          float p = prob[token];
          float* dst = Cf + (size_t)token * N + n0 + wc * (BN / 2) + lr;
#pragma unroll
          for (int ni = 0; ni < NI; ++ni) dst[ni * 16] = acc[mi][ni][r] * p;
        }
      }
    }
  }
}

extern "C" void kernel_launch(void* const* d_in, const int* in_sizes, int n_in,
                              void* d_out, int out_size, void* d_ws, size_t ws_size,
                              hipStream_t stream) {
  const float* X = (const float*)d_in[0];
  const float* Wr = (const float*)d_in[1];
  const float* W1 = (const float*)d_in[2];
  const float* W2 = (const float*)d_in[3];

  float* out_states = (float*)d_out;
  float* out_logits = out_states + (size_t)T_TOKENS * H_DIM;
  float* out_index = out_logits + (size_t)T_TOKENS * E_NUM;

  char* ws = (char*)d_ws;
  int* counts = (int*)(ws + 0);       // 8 ints
  int* cursor = (int*)(ws + 32);      // 8 ints
  int* offs = (int*)(ws + 64);        // 9 ints
  int* expert = (int*)(ws + 128);     // 2048 ints
  float* prob = (float*)(ws + 8320);  // 2048 f32
  int* perm = (int*)(ws + 16512);     // 2048 ints
  __hip_bfloat16* xg = (__hip_bfloat16*)(ws + 24704);      // 2048*768 bf16
  __hip_bfloat16* hbuf = (__hip_bfloat16*)(ws + 3170432);  // 2048*3072 bf16
  // total ws use ~15.76 MB

  hipMemsetAsync(d_ws, 0, 64, stream);  // zero counts + cursor

  router_kernel<<<T_TOKENS / 4, 256, 0, stream>>>(X, Wr, out_logits, out_index, expert, prob, counts);
  scan_kernel<<<1, 64, 0, stream>>>(counts, offs);
  scatter_kernel<<<T_TOKENS / 256, 256, 0, stream>>>(expert, offs, cursor, perm);
  gather_kernel<<<T_TOKENS / 4, 256, 0, stream>>>(X, perm, xg);

  // h = relu(xg @ W1[e]) : K=768, N=3072 -> ~768 active blocks
  moe_gemm<1, 128><<<dim3(F_DIM / 128, T_TOKENS / 64, E_NUM), 256, 0, stream>>>(
      xg, W1, hbuf, nullptr, offs, nullptr, nullptr, H_DIM, F_DIM);
  // y = (h @ W2[e]) * prob, scattered : K=3072, N=768 -> ~384 active blocks
  moe_gemm<0, 64><<<dim3(H_DIM / 64, T_TOKENS / 64, E_NUM), 256, 0, stream>>>(
      hbuf, W2, nullptr, out_states, offs, perm, prob, F_DIM, H_DIM);
}

// Round 3
// 159.103 us; speedup vs baseline: 1.4521x; 1.0695x over previous
//
#include <hip/hip_runtime.h>
#include <hip/hip_bf16.h>

// Switch MoE (top-1), B=2 S=1024 H=768 F=3072 E=8 on MI355X.
// Outputs concat in d_out: next_states[2048*768] f32, router_logits[2048*8] f32,
// expert_index[2048] written as float values.

#define T_TOKENS 2048
#define H_DIM 768
#define F_DIM 3072
#define E_NUM 8

typedef __attribute__((ext_vector_type(8))) short bf16x8;
typedef __attribute__((ext_vector_type(4))) float f32x4;

__device__ inline unsigned short f2bf(float f) {
  __hip_bfloat16 b = __float2bfloat16(f);
  return *reinterpret_cast<unsigned short*>(&b);
}
__device__ inline unsigned int pack2(float lo, float hi) {
  return (unsigned int)f2bf(lo) | ((unsigned int)f2bf(hi) << 16);
}
// LDS tiles are [row][64 bf16] = 128B rows, 8 x 16B slots per row.
// XOR-swizzle slot with (row&7): fragment ds_read_b128 phases (8 lanes, 8
// consecutive rows, same slot) then span all 32 banks -> conflict-free.
__device__ inline int swz(int row, int col) {
  return (row << 6) | (col & 7) | ((((col >> 3) ^ row) & 7) << 3);
}

// ---------------- Router: one wave per token ----------------
__global__ void router_kernel(const float* __restrict__ X, const float* __restrict__ Wr,
                              float* __restrict__ logits, float* __restrict__ idx_out,
                              int* __restrict__ expert, float* __restrict__ prob,
                              int* __restrict__ counts) {
  int wave = threadIdx.x >> 6, lane = threadIdx.x & 63;
  int t = blockIdx.x * 4 + wave;
  if (t >= T_TOKENS) return;
  const float* x = X + (size_t)t * H_DIM;
  float acc[E_NUM];
#pragma unroll
  for (int e = 0; e < E_NUM; ++e) acc[e] = 0.f;
  int h0 = lane * 12;  // 64 lanes * 12 = 768
#pragma unroll
  for (int j = 0; j < 12; ++j) {
    float xv = x[h0 + j];
    const float4* wr = reinterpret_cast<const float4*>(Wr + (size_t)(h0 + j) * E_NUM);
    float4 w0 = wr[0], w1 = wr[1];
    acc[0] += xv * w0.x; acc[1] += xv * w0.y; acc[2] += xv * w0.z; acc[3] += xv * w0.w;
    acc[4] += xv * w1.x; acc[5] += xv * w1.y; acc[6] += xv * w1.z; acc[7] += xv * w1.w;
  }
#pragma unroll
  for (int e = 0; e < E_NUM; ++e) {
#pragma unroll
    for (int s = 32; s > 0; s >>= 1) acc[e] += __shfl_down(acc[e], s);
  }
  if (lane == 0) {
    float m = acc[0]; int am = 0;
#pragma unroll
    for (int e = 1; e < E_NUM; ++e) {
      if (acc[e] > m) { m = acc[e]; am = e; }  // strict > keeps first occurrence (jnp.argmax)
    }
    float sum = 0.f;
#pragma unroll
    for (int e = 0; e < E_NUM; ++e) sum += __expf(acc[e] - m);
    float p = 1.f / sum;  // softmax prob of the argmax
#pragma unroll
    for (int e = 0; e < E_NUM; ++e) logits[(size_t)t * E_NUM + e] = acc[e];
    idx_out[t] = (float)am;
    expert[t] = am;
    prob[t] = p;
    atomicAdd(&counts[am], 1);
  }
}

// ---------------- Fused scan + scatter (one block, LDS cursors) ----------------
__global__ void scan_scatter_kernel(const int* __restrict__ counts,
                                    const int* __restrict__ expert,
                                    int* __restrict__ offs, int* __restrict__ perm) {
  __shared__ int so[E_NUM + 1];
  __shared__ int cur[E_NUM];
  int tid = threadIdx.x;
  if (tid == 0) {
    int s = 0;
    for (int e = 0; e < E_NUM; ++e) { so[e] = s; s += counts[e]; }
    so[E_NUM] = s;
  }
  if (tid < E_NUM) cur[tid] = 0;
  __syncthreads();
  if (tid < E_NUM + 1) offs[tid] = so[tid];
  for (int i = tid; i < T_TOKENS; i += blockDim.x) {
    int e = expert[i];
    int pos = atomicAdd(&cur[e], 1);
    perm[so[e] + pos] = i;
  }
}

// ---------------- Gather X rows -> contiguous bf16, one wave per row ----------------
__global__ void gather_kernel(const float* __restrict__ X, const int* __restrict__ perm,
                              __hip_bfloat16* __restrict__ xg) {
  int wave = threadIdx.x >> 6, lane = threadIdx.x & 63;
  int g = blockIdx.x * 4 + wave;
  if (g >= T_TOKENS) return;
  int token = perm[g];
  const float4* src = reinterpret_cast<const float4*>(X + (size_t)token * H_DIM + lane * 12);
  __hip_bfloat16* dst = xg + (size_t)g * H_DIM + lane * 12;
#pragma unroll
  for (int i = 0; i < 3; ++i) {
    float4 v = src[i];
    ushort4 u;
    u.x = f2bf(v.x); u.y = f2bf(v.y); u.z = f2bf(v.z); u.w = f2bf(v.w);
    *reinterpret_cast<ushort4*>(dst + i * 4) = u;
  }
}

// ---------------- Grouped GEMM: C[m,n] = sum_k A[m,k] * W[e][k,n] ----------------
// BM=BN=BK=64, 8 waves (4m x 2n grid), wavetile 16x32. Double-buffered
// XOR-swizzled LDS (32 KB), one barrier per K-step, next-tile global loads
// issued before the MFMA phase. B (f32 [K][N]) transposed to bf16 Bs[n][k]
// via in-register k-pair packing.
template <int RELU>
__global__ __launch_bounds__(512) void moe_gemm(
    const __hip_bfloat16* __restrict__ A, const float* __restrict__ Wt,
    __hip_bfloat16* __restrict__ Cbf, float* __restrict__ Cf,
    const int* __restrict__ offs, const int* __restrict__ perm,
    const float* __restrict__ prob, int K, int N) {
  constexpr int BM = 64, BN = 64, BK = 64;
  __shared__ __hip_bfloat16 As[2][BM * 64];
  __shared__ __hip_bfloat16 Bs[2][BN * 64];

  const int e = blockIdx.z;
  const int base = offs[e], cnt = offs[e + 1] - base;
  const int m0 = blockIdx.y * BM;
  if (m0 >= cnt) return;
  const int rows = min(BM, cnt - m0);
  const int n0 = blockIdx.x * BN;
  const __hip_bfloat16* __restrict__ Ab = A + (size_t)(base + m0) * K;
  const float* __restrict__ W = Wt + (size_t)e * K * N;

  const int tid = threadIdx.x;
  const int lane = tid & 63, wv = tid >> 6;
  const int wr = wv >> 1, wc = wv & 1;   // 4m x 2n wave grid
  const int lr = lane & 15, lg = lane >> 4;

  // A staging: thread -> (row, 16B slot). 64 rows x 8 slots = 512 threads.
  const int arow = tid >> 3, acol = (tid & 7) * 8;
  const __hip_bfloat16* Aptr = Ab + (size_t)min(arow, rows - 1) * K + acol;

  // B staging: thread -> (4 n-cols, 2 k-rows).
  const int bn4 = (tid & 15) * 4;
  const int bk = (tid >> 4) * 2;
  const float* Bptr = W + (size_t)bk * N + n0 + bn4;

  f32x4 acc[2];
  acc[0] = (f32x4){0.f, 0.f, 0.f, 0.f};
  acc[1] = (f32x4){0.f, 0.f, 0.f, 0.f};

  int4 aR;
  f32x4 f4[2];

#define LOAD_TILE(K0) do {                                                      \
    aR = *reinterpret_cast<const int4*>(Aptr + (K0));                           \
    f4[0] = *reinterpret_cast<const f32x4*>(Bptr + (size_t)(K0) * N);           \
    f4[1] = *reinterpret_cast<const f32x4*>(Bptr + (size_t)((K0) + 1) * N);     \
  } while (0)

#define WRITE_TILE(BUF) do {                                                    \
    *reinterpret_cast<int4*>(&As[BUF][swz(arow, acol)]) = aR;                   \
    _Pragma("unroll")                                                           \
    for (int cc = 0; cc < 4; ++cc)                                              \
      *reinterpret_cast<unsigned int*>(&Bs[BUF][swz(bn4 + cc, bk)]) =           \
          pack2(f4[0][cc], f4[1][cc]);                                          \
  } while (0)

  LOAD_TILE(0);
  WRITE_TILE(0);
  __syncthreads();

  const int nt = K / BK;
  int cb = 0;
  for (int t = 0; t < nt; ++t) {
    const bool pf = (t + 1) < nt;
    if (pf) LOAD_TILE((t + 1) * BK);  // issue early; consumed after MFMA phase

#pragma unroll
    for (int ks = 0; ks < 2; ++ks) {
      bf16x8 af = *reinterpret_cast<const bf16x8*>(&As[cb][swz(wr * 16 + lr, ks * 32 + lg * 8)]);
#pragma unroll
      for (int ni = 0; ni < 2; ++ni) {
        bf16x8 bv = *reinterpret_cast<const bf16x8*>(
            &Bs[cb][swz(wc * 32 + ni * 16 + lr, ks * 32 + lg * 8)]);
        acc[ni] = __builtin_amdgcn_mfma_f32_16x16x32_bf16(af, bv, acc[ni], 0, 0, 0);
      }
    }

    if (pf) WRITE_TILE(cb ^ 1);  // cb^1 fully consumed at end of iter t-1
    __syncthreads();
    cb ^= 1;
  }
#undef LOAD_TILE
#undef WRITE_TILE

  // ---- epilogue: C/D frag row=(lane>>4)*4+reg, col=lane&15 ----
#pragma unroll
  for (int r = 0; r < 4; ++r) {
    int row = wr * 16 + lg * 4 + r;
    if (row < rows) {
      if (RELU) {
        __hip_bfloat16* dst = Cbf + (size_t)(base + m0 + row) * N + n0 + wc * 32 + lr;
#pragma unroll
        for (int ni = 0; ni < 2; ++ni) {
          float v = acc[ni][r];
          dst[ni * 16] = __float2bfloat16(v > 0.f ? v : 0.f);
        }
      } else {
        int token = perm[base + m0 + row];
        float p = prob[token];
        float* dst = Cf + (size_t)token * N + n0 + wc * 32 + lr;
#pragma unroll
        for (int ni = 0; ni < 2; ++ni) dst[ni * 16] = acc[ni][r] * p;
      }
    }
  }
}

extern "C" void kernel_launch(void* const* d_in, const int* in_sizes, int n_in,
                              void* d_out, int out_size, void* d_ws, size_t ws_size,
                              hipStream_t stream) {
  const float* X = (const float*)d_in[0];
  const float* Wr = (const float*)d_in[1];
  const float* W1 = (const float*)d_in[2];
  const float* W2 = (const float*)d_in[3];

  float* out_states = (float*)d_out;
  float* out_logits = out_states + (size_t)T_TOKENS * H_DIM;
  float* out_index = out_logits + (size_t)T_TOKENS * E_NUM;

  char* ws = (char*)d_ws;
  int* counts = (int*)(ws + 0);       // 8 ints
  int* offs = (int*)(ws + 64);        // 9 ints
  int* expert = (int*)(ws + 128);     // 2048 ints
  float* prob = (float*)(ws + 8320);  // 2048 f32
  int* perm = (int*)(ws + 16512);     // 2048 ints
  __hip_bfloat16* xg = (__hip_bfloat16*)(ws + 24704);      // 2048*768 bf16
  __hip_bfloat16* hbuf = (__hip_bfloat16*)(ws + 3170432);  // 2048*3072 bf16
  // total ws use ~15.76 MB

  hipMemsetAsync(d_ws, 0, 64, stream);  // zero counts

  router_kernel<<<T_TOKENS / 4, 256, 0, stream>>>(X, Wr, out_logits, out_index, expert, prob, counts);
  scan_scatter_kernel<<<1, 1024, 0, stream>>>(counts, expert, offs, perm);
  gather_kernel<<<T_TOKENS / 4, 256, 0, stream>>>(X, perm, xg);

  // h = relu(xg @ W1[e]) : K=768, N=3072 -> ~1536 active blocks x 8 waves
  moe_gemm<1><<<dim3(F_DIM / 64, T_TOKENS / 64, E_NUM), 512, 0, stream>>>(
      xg, W1, hbuf, nullptr, offs, nullptr, nullptr, H_DIM, F_DIM);
  // y = (h @ W2[e]) * prob, scattered : K=3072, N=768 -> ~384 active blocks x 8 waves
  moe_gemm<0><<<dim3(H_DIM / 64, T_TOKENS / 64, E_NUM), 512, 0, stream>>>(
      hbuf, W2, nullptr, out_states, offs, perm, prob, F_DIM, H_DIM);
}

// Round 4
// 111.607 us; speedup vs baseline: 2.0700x; 1.4256x over previous
//
#include <hip/hip_runtime.h>
#include <hip/hip_bf16.h>

// Switch MoE (top-1), B=2 S=1024 H=768 F=3072 E=8 on MI355X.
// Outputs concat in d_out: next_states[2048*768] f32, router_logits[2048*8] f32,
// expert_index[2048] written as float values.

#define T_TOKENS 2048
#define H_DIM 768
#define F_DIM 3072
#define E_NUM 8
#define MSLOTS 40  // max sum_e ceil(cnt_e/64) = 32 + 7, padded

typedef __attribute__((ext_vector_type(8))) short bf16x8;
typedef __attribute__((ext_vector_type(4))) float f32x4;

__device__ inline unsigned short f2bf(float f) {
  __hip_bfloat16 b = __float2bfloat16(f);
  return *reinterpret_cast<unsigned short*>(&b);
}
__device__ inline unsigned int pack2(float lo, float hi) {
  return (unsigned int)f2bf(lo) | ((unsigned int)f2bf(hi) << 16);
}

// ---------------- Router: one wave per token ----------------
__global__ void router_kernel(const float* __restrict__ X, const float* __restrict__ Wr,
                              float* __restrict__ logits, float* __restrict__ idx_out,
                              int* __restrict__ expert, float* __restrict__ prob,
                              int* __restrict__ counts) {
  int wave = threadIdx.x >> 6, lane = threadIdx.x & 63;
  int t = blockIdx.x * 4 + wave;
  if (t >= T_TOKENS) return;
  const float* x = X + (size_t)t * H_DIM;
  float acc[E_NUM];
#pragma unroll
  for (int e = 0; e < E_NUM; ++e) acc[e] = 0.f;
  int h0 = lane * 12;
#pragma unroll
  for (int j = 0; j < 12; ++j) {
    float xv = x[h0 + j];
    const float4* wr = reinterpret_cast<const float4*>(Wr + (size_t)(h0 + j) * E_NUM);
    float4 w0 = wr[0], w1 = wr[1];
    acc[0] += xv * w0.x; acc[1] += xv * w0.y; acc[2] += xv * w0.z; acc[3] += xv * w0.w;
    acc[4] += xv * w1.x; acc[5] += xv * w1.y; acc[6] += xv * w1.z; acc[7] += xv * w1.w;
  }
#pragma unroll
  for (int e = 0; e < E_NUM; ++e) {
#pragma unroll
    for (int s = 32; s > 0; s >>= 1) acc[e] += __shfl_down(acc[e], s);
  }
  if (lane == 0) {
    float m = acc[0]; int am = 0;
#pragma unroll
    for (int e = 1; e < E_NUM; ++e) {
      if (acc[e] > m) { m = acc[e]; am = e; }  // strict > == jnp.argmax first-occurrence
    }
    float sum = 0.f;
#pragma unroll
    for (int e = 0; e < E_NUM; ++e) sum += __expf(acc[e] - m);
    float p = 1.f / sum;
#pragma unroll
    for (int e = 0; e < E_NUM; ++e) logits[(size_t)t * E_NUM + e] = acc[e];
    idx_out[t] = (float)am;
    expert[t] = am;
    prob[t] = p;
    atomicAdd(&counts[am], 1);
  }
}

// ------------- Fused scan + scatter + m-slot table (one block) -------------
__global__ void scan_scatter_kernel(const int* __restrict__ counts,
                                    const int* __restrict__ expert,
                                    int* __restrict__ offs, int* __restrict__ perm,
                                    int* __restrict__ mse, int* __restrict__ msm0) {
  __shared__ int so[E_NUM + 1];
  __shared__ int cur[E_NUM];
  int tid = threadIdx.x;
  if (tid == 0) {
    int s = 0;
    for (int e = 0; e < E_NUM; ++e) { so[e] = s; s += counts[e]; }
    so[E_NUM] = s;
    // build m-slot table: (expert, m0) pairs, 64-row tiles
    int ns = 0;
    for (int e = 0; e < E_NUM; ++e)
      for (int m0 = 0; m0 < counts[e]; m0 += 64) { mse[ns] = e; msm0[ns] = m0; ++ns; }
    for (; ns < MSLOTS; ++ns) { mse[ns] = -1; msm0[ns] = 0; }
  }
  if (tid < E_NUM) cur[tid] = 0;
  __syncthreads();
  if (tid < E_NUM + 1) offs[tid] = so[tid];
  for (int i = tid; i < T_TOKENS; i += blockDim.x) {
    int e = expert[i];
    int pos = atomicAdd(&cur[e], 1);
    perm[so[e] + pos] = i;
  }
}

// ---------------- Gather X rows -> contiguous bf16 ----------------
__global__ void gather_kernel(const float* __restrict__ X, const int* __restrict__ perm,
                              __hip_bfloat16* __restrict__ xg) {
  int wave = threadIdx.x >> 6, lane = threadIdx.x & 63;
  int g = blockIdx.x * 4 + wave;
  if (g >= T_TOKENS) return;
  int token = perm[g];
  const float4* src = reinterpret_cast<const float4*>(X + (size_t)token * H_DIM + lane * 12);
  __hip_bfloat16* dst = xg + (size_t)g * H_DIM + lane * 12;
#pragma unroll
  for (int i = 0; i < 3; ++i) {
    float4 v = src[i];
    ushort4 u;
    u.x = f2bf(v.x); u.y = f2bf(v.y); u.z = f2bf(v.z); u.w = f2bf(v.w);
    *reinterpret_cast<ushort4*>(dst + i * 4) = u;
  }
}

// ---------------- Grouped GEMM, depth-3 pipelined ----------------
// C[m,n] = sum_k A[m,k] * W[e][k,n]. BM=64, BN=128, BK=64, 8 waves (4m x 2n),
// wavetile 16x64. 3 LDS buffers, prefetch 3 tiles ahead, counted vmcnt via
// compiler scoreboard + raw s_barrier (no vmcnt(0) drain in main loop).
// LDS rows are 128B = 8 x 16B slots, XOR-swizzled: slot' = slot ^ (row&7);
// all staging writes (b128) and fragment reads (ds_read_b128) conflict-free.
template <int RELU, int K, int N>
__global__ __launch_bounds__(512, 4) void moe_gemm(
    const __hip_bfloat16* __restrict__ A, const float* __restrict__ Wt,
    __hip_bfloat16* __restrict__ Cbf, float* __restrict__ Cf,
    const int* __restrict__ offs, const int* __restrict__ perm,
    const float* __restrict__ prob, const int* __restrict__ mse,
    const int* __restrict__ msm0) {
  constexpr int ABUF = 64 * 128;           // 8 KB
  constexpr int BBUF = 128 * 128;          // 16 KB
  constexpr int BUFSZ = ABUF + BBUF;       // 24 KB
  constexpr int nt = K / 64;
  __shared__ __align__(16) char lds[3 * BUFSZ];

  // ---- work decode with XCD-chunk swizzle ----
  const int nw = gridDim.x;                // multiple of 8
  const int cpx = nw >> 3;
  const int d = blockIdx.x;
  const int w = (d & 7) * cpx + (d >> 3);  // consecutive w -> same XCD
  const int nt_i = w / MSLOTS, slot = w - nt_i * MSLOTS;
  const int e = mse[slot];
  if (e < 0) return;
  const int base = offs[e], cnt = offs[e + 1] - base;
  const int m0 = msm0[slot];
  const int rows = min(64, cnt - m0);
  const int n0 = nt_i * 128;

  const int tid = threadIdx.x;
  const int lane = tid & 63, wv = tid >> 6;
  const int wr = wv >> 1, wc = wv & 1;
  const int lr = lane & 15, lg = lane >> 4;

  // ---- staging addresses ----
  const int m_a = tid >> 3, sl_a = tid & 7;
  const __hip_bfloat16* Ap = A + (size_t)(base + m0 + min(m_a, rows - 1)) * K + sl_a * 8;
  const int a_woff = m_a * 128 + (((sl_a ^ (m_a & 7))) << 4);

  const int n_b = tid & 127, kg = tid >> 7;  // thread: 1 n-col, k = kg*16+i
  const float* Bp = Wt + (size_t)e * K * N + (size_t)(kg * 16) * N + n0 + n_b;
  const int b_woff0 = ABUF + n_b * 128 + (((2 * kg) ^ (n_b & 7)) << 4);
  const int b_woff1 = ABUF + n_b * 128 + (((2 * kg + 1) ^ (n_b & 7)) << 4);

  // ---- fragment LDS offsets (conflict-free swizzled reads) ----
  const int ar = wr * 16 + lr;
  int aof[2], bof[2][4];
#pragma unroll
  for (int ks = 0; ks < 2; ++ks) {
    aof[ks] = ar * 128 + (((ks * 4 + lg) ^ (ar & 7)) << 4);
#pragma unroll
    for (int ni = 0; ni < 4; ++ni) {
      int br = wc * 64 + ni * 16 + lr;
      bof[ks][ni] = ABUF + br * 128 + (((ks * 4 + lg) ^ (br & 7)) << 4);
    }
  }

  f32x4 acc[4];
#pragma unroll
  for (int i = 0; i < 4; ++i) acc[i] = (f32x4){0.f, 0.f, 0.f, 0.f};

  int4 aq0, aq1;
  float bq0[16], bq1[16];

#define LOADT(RS, T) {                                                          \
    aq##RS = *reinterpret_cast<const int4*>(Ap + (size_t)(T) * 64);             \
    _Pragma("unroll")                                                           \
    for (int i = 0; i < 16; ++i) bq##RS[i] = Bp[(size_t)((T) * 64 + i) * N];    \
  }

#define WRITET(BUF, RS) {                                                       \
    char* base_ = lds + (BUF) * BUFSZ;                                          \
    *reinterpret_cast<int4*>(base_ + a_woff) = aq##RS;                          \
    int4 u0_, u1_;                                                              \
    u0_.x = (int)pack2(bq##RS[0], bq##RS[1]);                                   \
    u0_.y = (int)pack2(bq##RS[2], bq##RS[3]);                                   \
    u0_.z = (int)pack2(bq##RS[4], bq##RS[5]);                                   \
    u0_.w = (int)pack2(bq##RS[6], bq##RS[7]);                                   \
    u1_.x = (int)pack2(bq##RS[8], bq##RS[9]);                                   \
    u1_.y = (int)pack2(bq##RS[10], bq##RS[11]);                                 \
    u1_.z = (int)pack2(bq##RS[12], bq##RS[13]);                                 \
    u1_.w = (int)pack2(bq##RS[14], bq##RS[15]);                                 \
    *reinterpret_cast<int4*>(base_ + b_woff0) = u0_;                            \
    *reinterpret_cast<int4*>(base_ + b_woff1) = u1_;                            \
  }

#define MFMA_STEP(BUF) {                                                        \
    const char* base_ = lds + (BUF) * BUFSZ;                                    \
    _Pragma("unroll")                                                           \
    for (int ks = 0; ks < 2; ++ks) {                                            \
      bf16x8 av = *reinterpret_cast<const bf16x8*>(base_ + aof[ks]);            \
      _Pragma("unroll")                                                         \
      for (int ni = 0; ni < 4; ++ni) {                                          \
        bf16x8 bv = *reinterpret_cast<const bf16x8*>(base_ + bof[ks][ni]);      \
        acc[ni] = __builtin_amdgcn_mfma_f32_16x16x32_bf16(av, bv, acc[ni], 0, 0, 0); \
      }                                                                         \
    }                                                                           \
  }

#define SYNC() {                                                                \
    asm volatile("s_waitcnt lgkmcnt(0)" ::: "memory");                          \
    __builtin_amdgcn_s_barrier();                                               \
    asm volatile("" ::: "memory");                                              \
  }

#define STEP(T, BUF, WBUF, RS) {                                                \
    MFMA_STEP(BUF);                                                             \
    if ((T) + 1 < nt) WRITET(WBUF, RS);                                         \
    if ((T) + 3 < nt) LOADT(RS, (T) + 3);                                       \
    SYNC();                                                                     \
  }

  // prologue: tiles 0,1,2 in flight; tile0 written to buf0
  LOADT(0, 0);
  LOADT(1, 1);
  WRITET(0, 0);   // compiler: counted vmcnt (tile1 loads stay outstanding)
  LOADT(0, 2);
  SYNC();

  for (int t0 = 0; t0 < nt; t0 += 6) {
    STEP(t0 + 0, 0, 1, 1);
    STEP(t0 + 1, 1, 2, 0);
    STEP(t0 + 2, 2, 0, 1);
    STEP(t0 + 3, 0, 1, 0);
    STEP(t0 + 4, 1, 2, 1);
    STEP(t0 + 5, 2, 0, 0);
  }
#undef LOADT
#undef WRITET
#undef MFMA_STEP
#undef SYNC
#undef STEP

  // ---- epilogue: C/D frag row=(lane>>4)*4+reg, col=lane&15 ----
#pragma unroll
  for (int r = 0; r < 4; ++r) {
    int row = wr * 16 + lg * 4 + r;
    if (row < rows) {
      if (RELU) {
        __hip_bfloat16* dst = Cbf + (size_t)(base + m0 + row) * N + n0 + wc * 64 + lr;
#pragma unroll
        for (int ni = 0; ni < 4; ++ni) {
          float v = acc[ni][r];
          dst[ni * 16] = __float2bfloat16(v > 0.f ? v : 0.f);
        }
      } else {
        int token = perm[base + m0 + row];
        float p = prob[token];
        float* dst = Cf + (size_t)token * N + n0 + wc * 64 + lr;
#pragma unroll
        for (int ni = 0; ni < 4; ++ni) dst[ni * 16] = acc[ni][r] * p;
      }
    }
  }
}

extern "C" void kernel_launch(void* const* d_in, const int* in_sizes, int n_in,
                              void* d_out, int out_size, void* d_ws, size_t ws_size,
                              hipStream_t stream) {
  const float* X = (const float*)d_in[0];
  const float* Wr = (const float*)d_in[1];
  const float* W1 = (const float*)d_in[2];
  const float* W2 = (const float*)d_in[3];

  float* out_states = (float*)d_out;
  float* out_logits = out_states + (size_t)T_TOKENS * H_DIM;
  float* out_index = out_logits + (size_t)T_TOKENS * E_NUM;

  char* ws = (char*)d_ws;
  int* counts = (int*)(ws + 0);        // 8 ints
  int* offs = (int*)(ws + 64);         // 9 ints
  int* expert = (int*)(ws + 128);      // 2048 ints
  float* prob = (float*)(ws + 8320);   // 2048 f32
  int* perm = (int*)(ws + 16512);      // 2048 ints
  int* mse = (int*)(ws + 24704);       // 40 ints
  int* msm0 = (int*)(ws + 24896);      // 40 ints
  __hip_bfloat16* xg = (__hip_bfloat16*)(ws + 25088);      // 2048*768 bf16
  __hip_bfloat16* hbuf = (__hip_bfloat16*)(ws + 3170816);  // 2048*3072 bf16 (aligned 16)

  hipMemsetAsync(d_ws, 0, 64, stream);  // zero counts

  router_kernel<<<T_TOKENS / 4, 256, 0, stream>>>(X, Wr, out_logits, out_index, expert, prob, counts);
  scan_scatter_kernel<<<1, 1024, 0, stream>>>(counts, expert, offs, perm, mse, msm0);
  gather_kernel<<<T_TOKENS / 4, 256, 0, stream>>>(X, perm, xg);

  // h = relu(xg @ W1[e]) : K=768, N=3072 -> 24 n-tiles x 40 slots = 960 blocks
  moe_gemm<1, H_DIM, F_DIM><<<(F_DIM / 128) * MSLOTS, 512, 0, stream>>>(
      xg, W1, hbuf, nullptr, offs, nullptr, nullptr, mse, msm0);
  // y = (h @ W2[e]) * prob, scattered : K=3072, N=768 -> 6 x 40 = 240 blocks
  moe_gemm<0, F_DIM, H_DIM><<<(H_DIM / 128) * MSLOTS, 512, 0, stream>>>(
      hbuf, W2, nullptr, out_states, offs, perm, prob, mse, msm0);
}